// Round 3
// baseline (949.094 us; speedup 1.0000x reference)
//
#include <hip/hip_runtime.h>
#include <stdint.h>

typedef unsigned short u16;
typedef unsigned int   u32;

static constexpr float kScale = 0.17677669529663687f; // HD^-0.5

// ---------- bf16 helpers (bf16 carried as u16) ----------
__device__ __forceinline__ float bfl(u32 dw){ union{u32 u; float f;} x; x.u = dw << 16;        return x.f; }
__device__ __forceinline__ float bfh(u32 dw){ union{u32 u; float f;} x; x.u = dw & 0xffff0000u; return x.f; }
__device__ __forceinline__ float bf2f(u16 v){ union{u32 u; float f;} x; x.u = ((u32)v) << 16;  return x.f; }
__device__ __forceinline__ u16  f2bf(float f){
  union{float f; u32 u;} x; x.f = f;
  u32 r = x.u + 0x7fffu + ((x.u >> 16) & 1u);  // RNE
  return (u16)(r >> 16);
}

// ---------------------------------------------------------------------------
// D0: dtype detect. Reads first 64 even u16s of in_proj_bias. If the raw data
// is f32, even u16s are mantissa halves -> decode as bf16 to huge/NaN values.
// If data is bf16, all values ~N(0,0.02). flag=1 means "inputs are f32".
// ---------------------------------------------------------------------------
__global__ void detect_kernel(const u16* __restrict__ bias, int* __restrict__ flag){
  int tid = threadIdx.x;               // 64 threads
  u16 raw = bias[tid * 2];
  int big = (fabsf(bf2f(raw)) > 1e6f) ? 1 : 0;
  if ((raw & 0x7F80u) == 0x7F80u) big = 1;   // NaN/Inf bit pattern
  #pragma unroll
  for (int m = 1; m < 64; m <<= 1) big |= __shfl_xor(big, m);
  if (tid == 0) *flag = big;
}

// ---------------------------------------------------------------------------
// K0: row/col means of key_row (over h) and key_col (over w). f32 out.
// ---------------------------------------------------------------------------
__global__ void means_kernel(const void* __restrict__ key_row, const void* __restrict__ key_col,
                             float* __restrict__ krm, float* __restrict__ kcm,
                             const int* __restrict__ flag){
  const bool isf32 = (*flag != 0);
  int g   = blockIdx.x * 256 + threadIdx.x;  // 0..24575
  int c8  = (g & 31) * 8;
  int ri  = g >> 5;                          // 0..767
  int rw  = ri % 96;
  int n   = ri / 96;
  float acc[8];
  #pragma unroll
  for (int i = 0; i < 8; i++) acc[i] = 0.f;

  size_t base, stride;
  const void* src;
  float* dst;
  if (blockIdx.y == 0){         // krm: mean over h; rw = w
    src    = key_row;
    base   = ((size_t)(n*96)*96 + rw)*256 + c8;
    stride = (size_t)96*256;
    dst    = krm + ((size_t)(n*96) + rw)*256 + c8;
  } else {                      // kcm: mean over w; rw = h
    src    = key_col;
    base   = ((size_t)(n*96) + rw)*(size_t)(96*256) + c8;
    stride = 256;
    dst    = kcm + ((size_t)(n*96) + rw)*256 + c8;
  }

  if (isf32){
    const float* p = (const float*)src + base;
    for (int t = 0; t < 96; t++){
      float4 f0 = *(const float4*)(p + t*stride);
      float4 f1 = *(const float4*)(p + t*stride + 4);
      acc[0]+=f0.x; acc[1]+=f0.y; acc[2]+=f0.z; acc[3]+=f0.w;
      acc[4]+=f1.x; acc[5]+=f1.y; acc[6]+=f1.z; acc[7]+=f1.w;
    }
  } else {
    const u16* p = (const u16*)src + base;
    for (int t = 0; t < 96; t++){
      uint4 u = *(const uint4*)(p + t*stride);
      acc[0]+=bfl(u.x); acc[1]+=bfh(u.x); acc[2]+=bfl(u.y); acc[3]+=bfh(u.y);
      acc[4]+=bfl(u.z); acc[5]+=bfh(u.z); acc[6]+=bfl(u.w); acc[7]+=bfh(u.w);
    }
  }
  #pragma unroll
  for (int i = 0; i < 8; i++) dst[i] = acc[i] * (1.f/96.f);
}

// ---------------------------------------------------------------------------
// K1: GEMM  Y[m][j] = scale*( sum_k X[m][k]*W[j][k] + b[j] ), K=256.
// XK: 0 = X is ws f32, 2 = X is raw input (dtype per flag).
// OBF: 0 = f32 out, 1 = bf16 out, 2 = out dtype per flag (final output).
// OMAP 0: row-major [m][256]
// OMAP 1: out-proj remap m=(n*300+l) -> row l*8+n
// OMAP 3: v-proj head-group slice (W row = head0*32+col; store head-major slab)
// W, bias: always raw inputs (dtype per flag); element offsets wslice/boff.
// ---------------------------------------------------------------------------
template<int XK, int OBF, int OMAP>
__global__ void gemm256_kernel(const void* __restrict__ Xv,
                               const void* __restrict__ Wv, int wslice,
                               const void* __restrict__ Bv, int boff,
                               void* __restrict__ Yv,
                               int M, float scale, int head0, int hg,
                               const int* __restrict__ flag){
  const bool isf32 = (*flag != 0);
  __shared__ float Xs[64*17];
  __shared__ float Ws[64*17];
  int tid  = threadIdx.x;
  int m0   = blockIdx.x * 64;
  int j0   = blockIdx.y * 64;
  int lrow = tid >> 2;        // 0..63
  int lk   = (tid & 3) * 4;   // 0,4,8,12
  int tm   = tid >> 4, tj = tid & 15;
  float acc[4][4] = {};

  const bool xf32 = (XK == 0) || (XK == 2 && isf32);

  for (int p = 0; p < 16; p++){
    int k0 = p * 16;
    float xr[4], wr[4];
    int mrow = m0 + lrow;
    if (mrow < M){
      size_t xoff = (size_t)mrow*256 + k0 + lk;
      if (xf32){
        float4 f = *(const float4*)((const float*)Xv + xoff);
        xr[0]=f.x; xr[1]=f.y; xr[2]=f.z; xr[3]=f.w;
      } else {
        uint2 u = *(const uint2*)((const u16*)Xv + xoff);
        xr[0]=bfl(u.x); xr[1]=bfh(u.x); xr[2]=bfl(u.y); xr[3]=bfh(u.y);
      }
    } else { xr[0]=xr[1]=xr[2]=xr[3]=0.f; }

    int wrow = j0 + lrow;
    if (OMAP == 3){ wrow += head0*32; if (wrow > 255) wrow = 255; }
    size_t woff = (size_t)wslice*65536 + (size_t)wrow*256 + k0 + lk;
    if (isf32){
      float4 f = *(const float4*)((const float*)Wv + woff);
      wr[0]=f.x; wr[1]=f.y; wr[2]=f.z; wr[3]=f.w;
    } else {
      uint2 w2 = *(const uint2*)((const u16*)Wv + woff);
      wr[0]=bfl(w2.x); wr[1]=bfh(w2.x); wr[2]=bfl(w2.y); wr[3]=bfh(w2.y);
    }

    __syncthreads();
    #pragma unroll
    for (int i = 0; i < 4; i++){ Xs[lrow*17 + lk + i] = xr[i]; Ws[lrow*17 + lk + i] = wr[i]; }
    __syncthreads();

    #pragma unroll
    for (int kk = 0; kk < 16; kk++){
      float a[4], b[4];
      #pragma unroll
      for (int i = 0; i < 4; i++) a[i] = Xs[(tm*4 + i)*17 + kk];
      #pragma unroll
      for (int jx = 0; jx < 4; jx++) b[jx] = Ws[(tj*4 + jx)*17 + kk];
      #pragma unroll
      for (int i = 0; i < 4; i++)
        #pragma unroll
        for (int jx = 0; jx < 4; jx++) acc[i][jx] += a[i] * b[jx];
    }
  }

  float bv[4];
  #pragma unroll
  for (int jx = 0; jx < 4; jx++){
    int bidx = j0 + tj*4 + jx;
    if (OMAP == 3 && bidx > hg*32 - 1) bidx = hg*32 - 1;   // clamped values never stored
    bv[jx] = isf32 ? ((const float*)Bv)[boff + bidx] : bf2f(((const u16*)Bv)[boff + bidx]);
  }

  #pragma unroll
  for (int i = 0; i < 4; i++){
    int m = m0 + tm*4 + i;
    if (m >= M) continue;
    #pragma unroll
    for (int jx = 0; jx < 4; jx++){
      int col = j0 + tj*4 + jx;
      float vval = scale * (acc[i][jx] + bv[jx]);
      if (OMAP == 3){
        if (col < hg*32){
          int nn = m / 9216, hw = m - nn*9216;
          ((u16*)Yv)[ ((size_t)(nn*hg + (col >> 5))*9216 + hw)*32 + (col & 31) ] = f2bf(vval);
        }
      } else {
        int orow = (OMAP == 1) ? ((m % 300)*8 + (m / 300)) : m;
        size_t oidx = (size_t)orow*256 + col;
        if (OBF == 2){
          if (isf32) ((float*)Yv)[oidx] = vval; else ((u16*)Yv)[oidx] = f2bf(vval);
        } else if (OBF == 1) ((u16*)Yv)[oidx] = f2bf(vval);
        else                 ((float*)Yv)[oidx] = vval;
      }
    }
  }
}

// ---------------------------------------------------------------------------
// K2: attention weights for one head group. Block (128 thr) per (l, gs, row/col)
// where gs = n*hg + hr, head = head0 + hr. q bf16 (ws), k f32 (ws), a bf16 out.
// ---------------------------------------------------------------------------
__global__ void attn_weights_kernel(const u16* __restrict__ qr, const float* __restrict__ kr,
                                    const u16* __restrict__ qc, const float* __restrict__ kc,
                                    u16* __restrict__ arow, u16* __restrict__ acol,
                                    int head0, int hg){
  __shared__ float ks[96*33];   // pad 33: 96 % 32 == 0 would conflict
  __shared__ float qs[32];
  __shared__ float sred[2];
  int l  = blockIdx.x;
  int gs = blockIdx.y;                 // n*hg + hr
  int n  = gs / hg;
  int head = head0 + (gs % hg);
  const u16*   q = blockIdx.z ? qc : qr;
  const float* k = blockIdx.z ? kc : kr;
  u16*         a = blockIdx.z ? acol : arow;
  int tid = threadIdx.x;

  for (int i = tid; i < 96*32; i += 128){
    int w = i >> 5, d = i & 31;
    ks[w*33 + d] = k[((size_t)(n*96) + w)*256 + head*32 + d];
  }
  if (tid < 32) qs[tid] = bf2f(q[((size_t)(n*300) + l)*256 + head*32 + tid]);
  __syncthreads();

  float logit = -1e30f;
  if (tid < 96){
    float s = 0.f;
    #pragma unroll
    for (int d = 0; d < 32; d++) s += qs[d] * ks[tid*33 + d];
    logit = s;
  }
  float m = logit;
  #pragma unroll
  for (int mask = 1; mask < 64; mask <<= 1) m = fmaxf(m, __shfl_xor(m, mask));
  if ((tid & 63) == 0) sred[tid >> 6] = m;
  __syncthreads();
  float Mx = fmaxf(sred[0], sred[1]);
  float e  = (tid < 96) ? __expf(logit - Mx) : 0.f;
  float s  = e;
  #pragma unroll
  for (int mask = 1; mask < 64; mask <<= 1) s += __shfl_xor(s, mask);
  __syncthreads();
  if ((tid & 63) == 0) sred[tid >> 6] = s;
  __syncthreads();
  float S = sred[0] + sred[1];
  if (tid < 96) a[((size_t)gs*300 + l)*96 + tid] = f2bf(e / S);
}

// ---------------------------------------------------------------------------
// K3: core contraction for one head group.
// attn[n][l][head*32+d] = sum_h acol * (sum_w arow * V).
// v_slab bf16 [gs][h*96+w][32], gs = n*hg + hr. Grid (19 l-tiles, 8*hg).
// Block 256 thr = 16 l x 8 dq(4 d) x 2 h_i.
// ---------------------------------------------------------------------------
__global__ __launch_bounds__(256) void rcda_core_kernel(
    const u16* __restrict__ arow, const u16* __restrict__ acol,
    const u16* __restrict__ v, float* __restrict__ attn, int head0, int hg){
  __shared__ __align__(16) u16 vs[8*96*32];   // 49152 B
  __shared__ float as_[16*97];
  __shared__ float cs_[16*97];

  int lt  = blockIdx.x;                // 0..18
  int gs  = blockIdx.y;                // n*hg + hr
  int n   = gs / hg;
  int head = head0 + (gs % hg);
  int l0  = lt * 16;
  int tid = threadIdx.x;

  for (int i = tid; i < 16*96; i += 256){
    int li = i / 96, w = i - li*96;
    int lc = l0 + li; if (lc > 299) lc = 299;
    as_[li*97 + w] = bf2f(arow[((size_t)gs*300 + lc)*96 + w]);
    cs_[li*97 + w] = bf2f(acol[((size_t)gs*300 + lc)*96 + w]);
  }

  int l_i = tid & 15;
  int u   = tid >> 4;
  int dq  = u & 7;
  int h_i = u >> 3;
  const u16* vsl = v + (size_t)gs * 9216 * 32;

  float acc[4] = {0.f, 0.f, 0.f, 0.f};

  for (int cc = 0; cc < 12; cc++){
    __syncthreads();
    const u16* src = vsl + (size_t)cc * 8 * 3072;
    #pragma unroll
    for (int it = 0; it < 12; it++){
      int i = tid + it*256;            // 0..3071 uint4 groups
      *(uint4*)(vs + i*8) = *(const uint4*)(src + i*8);
    }
    __syncthreads();

    #pragma unroll
    for (int hh = 0; hh < 4; hh++){
      int h = h_i + hh*2;
      float t0=0.f, t1=0.f, t2=0.f, t3=0.f;
      const u16*   vrow = vs + h*96*32 + dq*4;
      const float* ar   = as_ + l_i*97;
      #pragma unroll 4
      for (int w = 0; w < 96; w++){
        uint2 pv = *(const uint2*)(vrow + w*32);
        float a  = ar[w];
        t0 += a * bfl(pv.x);
        t1 += a * bfh(pv.x);
        t2 += a * bfl(pv.y);
        t3 += a * bfh(pv.y);
      }
      float ac = cs_[l_i*97 + cc*8 + h];
      acc[0] += ac*t0; acc[1] += ac*t1; acc[2] += ac*t2; acc[3] += ac*t3;
    }
  }

  __syncthreads();
  float* red = as_;                    // reuse (512 floats)
  if (h_i == 1){
    #pragma unroll
    for (int k2 = 0; k2 < 4; k2++) red[(tid & 127)*4 + k2] = acc[k2];
  }
  __syncthreads();
  if (h_i == 0){
    int l = l0 + l_i;
    if (l < 300){
      float* dst = attn + ((size_t)(n*300) + l)*256 + head*32 + dq*4;
      #pragma unroll
      for (int k2 = 0; k2 < 4; k2++) dst[k2] = acc[k2] + red[tid*4 + k2];
    }
  }
}

// ---------------------------------------------------------------------------
// Workspace: flag(256B) | v_slab | arow | acol | qr | qc | krm | kcm | kr | kc | attn
// need(hg) = hg*5,640,192 + 8,061,184 bytes (53.2/30.6/19.3/13.7 MB for hg=8/4/2/1)
// ---------------------------------------------------------------------------
extern "C" void kernel_launch(void* const* d_in, const int* in_sizes, int n_in,
                              void* d_out, int out_size, void* d_ws, size_t ws_size,
                              hipStream_t stream){
  const void* query_row = d_in[0];
  const void* query_col = d_in[1];
  const void* key_row   = d_in[2];
  const void* key_col   = d_in[3];
  const void* value     = d_in[4];
  const void* in_w      = d_in[5];
  const void* in_b      = d_in[6];
  const void* out_w     = d_in[7];
  const void* out_b     = d_in[8];

  int hg = 1;
  {
    const size_t fixed = 8061184, per = 5640192;
    if      (ws_size >= fixed + 8*per) hg = 8;
    else if (ws_size >= fixed + 4*per) hg = 4;
    else if (ws_size >= fixed + 2*per) hg = 2;
    else                               hg = 1;
  }

  char* ws = (char*)d_ws;
  int*  flag = (int*)ws;
  size_t SV = (size_t)hg * 8 * 9216 * 32 * 2;  // v slab bf16
  size_t SA = (size_t)hg * 8 * 300 * 96 * 2;   // a slab bf16
  size_t off = 256;
  u16*   v_slab = (u16*)(ws + off); off += SV;
  u16*   arow   = (u16*)(ws + off); off += SA;
  u16*   acol   = (u16*)(ws + off); off += SA;
  u16*   qr     = (u16*)(ws + off); off += 1228800;
  u16*   qc     = (u16*)(ws + off); off += 1228800;
  float* krm    = (float*)(ws + off); off += 786432;
  float* kcm    = (float*)(ws + off); off += 786432;
  float* kr     = (float*)(ws + off); off += 786432;
  float* kc     = (float*)(ws + off); off += 786432;
  float* attn   = (float*)(ws + off); off += 2457600;

  // D0: dtype detection (flag=1 -> raw inputs are f32)
  detect_kernel<<<1, 64, 0, stream>>>((const u16*)in_b, flag);

  // K0: key means (mean commutes with the affine projection)
  means_kernel<<<dim3(96, 2), 256, 0, stream>>>(key_row, key_col, krm, kcm, flag);

  // K1: q projections (bf16 ws out) and mean-key projections (f32 ws out)
  gemm256_kernel<2,1,0><<<dim3(38, 4), 256, 0, stream>>>(query_row, in_w, 0, in_b, 0,   qr, 2400, kScale, 0, hg, flag);
  gemm256_kernel<2,1,0><<<dim3(38, 4), 256, 0, stream>>>(query_col, in_w, 1, in_b, 256, qc, 2400, kScale, 0, hg, flag);
  gemm256_kernel<0,0,0><<<dim3(12, 4), 256, 0, stream>>>(krm,       in_w, 2, in_b, 512, kr, 768,  1.f,    0, hg, flag);
  gemm256_kernel<0,0,0><<<dim3(12, 4), 256, 0, stream>>>(kcm,       in_w, 3, in_b, 768, kc, 768,  1.f,    0, hg, flag);

  // Per head group: v-proj slice -> softmax slice -> core slice
  for (int head0 = 0; head0 < 8; head0 += hg){
    int gy = (hg*32 + 63) / 64;   // 1,1,2,4 for hg=1,2,4,8
    gemm256_kernel<2,1,3><<<dim3(1152, gy), 256, 0, stream>>>(
        value, in_w, 4, in_b, 1024 + head0*32, v_slab, 73728, 1.f, head0, hg, flag);
    attn_weights_kernel<<<dim3(300, 8*hg, 2), 128, 0, stream>>>(qr, kr, qc, kc, arow, acol, head0, hg);
    rcda_core_kernel<<<dim3(19, 8*hg), 256, 0, stream>>>(arow, acol, v_slab, attn, head0, hg);
  }

  // K4: output projection, remap (n,l) -> row l*8+n, out dtype per flag
  gemm256_kernel<0,2,1><<<dim3(38, 4), 256, 0, stream>>>(attn, out_w, 0, out_b, 0, d_out, 2400, 1.f, 0, hg, flag);
}

// Round 4
// 603.161 us; speedup vs baseline: 1.5735x; 1.5735x over previous
//
#include <hip/hip_runtime.h>
#include <stdint.h>

typedef unsigned short u16;
typedef unsigned int   u32;
typedef __attribute__((ext_vector_type(8))) short bf16x8;
typedef __attribute__((ext_vector_type(4))) float f32x4;

static constexpr float kScale = 0.17677669529663687f; // HD^-0.5

// ---------- bf16 helpers (bf16 carried as u16) ----------
__device__ __forceinline__ float bfl(u32 dw){ union{u32 u; float f;} x; x.u = dw << 16;        return x.f; }
__device__ __forceinline__ float bfh(u32 dw){ union{u32 u; float f;} x; x.u = dw & 0xffff0000u; return x.f; }
__device__ __forceinline__ float bf2f(u16 v){ union{u32 u; float f;} x; x.u = ((u32)v) << 16;  return x.f; }
__device__ __forceinline__ u16  f2bf(float f){
  union{float f; u32 u;} x; x.f = f;
  u32 r = x.u + 0x7fffu + ((x.u >> 16) & 1u);  // RNE
  return (u16)(r >> 16);
}

// ---------------------------------------------------------------------------
// D0: dtype detect. flag=1 means "inputs are f32".
// ---------------------------------------------------------------------------
__global__ void detect_kernel(const u16* __restrict__ bias, int* __restrict__ flag){
  int tid = threadIdx.x;               // 64 threads
  u16 raw = bias[tid * 2];
  int big = (fabsf(bf2f(raw)) > 1e6f) ? 1 : 0;
  if ((raw & 0x7F80u) == 0x7F80u) big = 1;   // NaN/Inf bit pattern
  #pragma unroll
  for (int m = 1; m < 64; m <<= 1) big |= __shfl_xor(big, m);
  if (tid == 0) *flag = big;
}

// ---------------------------------------------------------------------------
// K0: row/col means of key_row (over h) and key_col (over w). f32 out.
// ---------------------------------------------------------------------------
__global__ void means_kernel(const void* __restrict__ key_row, const void* __restrict__ key_col,
                             float* __restrict__ krm, float* __restrict__ kcm,
                             const int* __restrict__ flag){
  const bool isf32 = (*flag != 0);
  int g   = blockIdx.x * 256 + threadIdx.x;  // 0..24575
  int c8  = (g & 31) * 8;
  int ri  = g >> 5;                          // 0..767
  int rw  = ri % 96;
  int n   = ri / 96;
  float acc[8];
  #pragma unroll
  for (int i = 0; i < 8; i++) acc[i] = 0.f;

  size_t base, stride;
  const void* src;
  float* dst;
  if (blockIdx.y == 0){         // krm: mean over h; rw = w
    src    = key_row;
    base   = ((size_t)(n*96)*96 + rw)*256 + c8;
    stride = (size_t)96*256;
    dst    = krm + ((size_t)(n*96) + rw)*256 + c8;
  } else {                      // kcm: mean over w; rw = h
    src    = key_col;
    base   = ((size_t)(n*96) + rw)*(size_t)(96*256) + c8;
    stride = 256;
    dst    = kcm + ((size_t)(n*96) + rw)*256 + c8;
  }

  if (isf32){
    const float* p = (const float*)src + base;
    for (int t = 0; t < 96; t++){
      float4 f0 = *(const float4*)(p + t*stride);
      float4 f1 = *(const float4*)(p + t*stride + 4);
      acc[0]+=f0.x; acc[1]+=f0.y; acc[2]+=f0.z; acc[3]+=f0.w;
      acc[4]+=f1.x; acc[5]+=f1.y; acc[6]+=f1.z; acc[7]+=f1.w;
    }
  } else {
    const u16* p = (const u16*)src + base;
    for (int t = 0; t < 96; t++){
      uint4 u = *(const uint4*)(p + t*stride);
      acc[0]+=bfl(u.x); acc[1]+=bfh(u.x); acc[2]+=bfl(u.y); acc[3]+=bfh(u.y);
      acc[4]+=bfl(u.z); acc[5]+=bfh(u.z); acc[6]+=bfl(u.w); acc[7]+=bfh(u.w);
    }
  }
  #pragma unroll
  for (int i = 0; i < 8; i++) dst[i] = acc[i] * (1.f/96.f);
}

// ---------------------------------------------------------------------------
// K1: GEMM  Y[m][j] = scale*( sum_k X[m][k]*W[j][k] + b[j] ), K=256.
// XK: 0 = X is ws f32, 2 = X is raw input (dtype per flag).
// OBF: 0 = f32 out, 1 = bf16 out, 2 = out dtype per flag (final output).
// OMAP 0: row-major [m][256]
// OMAP 1: out-proj remap m=(n*300+l) -> row l*8+n
// OMAP 3: v-proj slice -> TRANSPOSED slab Vt[gs][h][d][w], via LDS retile.
//         (W row = head0*32+col; gs = nn*hg + col>>5, d = col&31)
// ---------------------------------------------------------------------------
template<int XK, int OBF, int OMAP>
__global__ void gemm256_kernel(const void* __restrict__ Xv,
                               const void* __restrict__ Wv, int wslice,
                               const void* __restrict__ Bv, int boff,
                               void* __restrict__ Yv,
                               int M, float scale, int head0, int hg,
                               const int* __restrict__ flag){
  const bool isf32 = (*flag != 0);
  __shared__ float Xs[64*17];
  __shared__ float Ws[64*17];
  __shared__ u16 stile[64*66];   // only used by OMAP==3 retile epilogue
  int tid  = threadIdx.x;
  int m0   = blockIdx.x * 64;
  int j0   = blockIdx.y * 64;
  int lrow = tid >> 2;        // 0..63
  int lk   = (tid & 3) * 4;   // 0,4,8,12
  int tm   = tid >> 4, tj = tid & 15;
  float acc[4][4] = {};

  const bool xf32 = (XK == 0) || (XK == 2 && isf32);

  for (int p = 0; p < 16; p++){
    int k0 = p * 16;
    float xr[4], wr[4];
    int mrow = m0 + lrow;
    if (mrow < M){
      size_t xoff = (size_t)mrow*256 + k0 + lk;
      if (xf32){
        float4 f = *(const float4*)((const float*)Xv + xoff);
        xr[0]=f.x; xr[1]=f.y; xr[2]=f.z; xr[3]=f.w;
      } else {
        uint2 u = *(const uint2*)((const u16*)Xv + xoff);
        xr[0]=bfl(u.x); xr[1]=bfh(u.x); xr[2]=bfl(u.y); xr[3]=bfh(u.y);
      }
    } else { xr[0]=xr[1]=xr[2]=xr[3]=0.f; }

    int wrow = j0 + lrow;
    if (OMAP == 3){ wrow += head0*32; if (wrow > 255) wrow = 255; }
    size_t woff = (size_t)wslice*65536 + (size_t)wrow*256 + k0 + lk;
    if (isf32){
      float4 f = *(const float4*)((const float*)Wv + woff);
      wr[0]=f.x; wr[1]=f.y; wr[2]=f.z; wr[3]=f.w;
    } else {
      uint2 w2 = *(const uint2*)((const u16*)Wv + woff);
      wr[0]=bfl(w2.x); wr[1]=bfh(w2.x); wr[2]=bfl(w2.y); wr[3]=bfh(w2.y);
    }

    __syncthreads();
    #pragma unroll
    for (int i = 0; i < 4; i++){ Xs[lrow*17 + lk + i] = xr[i]; Ws[lrow*17 + lk + i] = wr[i]; }
    __syncthreads();

    #pragma unroll
    for (int kk = 0; kk < 16; kk++){
      float a[4], b[4];
      #pragma unroll
      for (int i = 0; i < 4; i++) a[i] = Xs[(tm*4 + i)*17 + kk];
      #pragma unroll
      for (int jx = 0; jx < 4; jx++) b[jx] = Ws[(tj*4 + jx)*17 + kk];
      #pragma unroll
      for (int i = 0; i < 4; i++)
        #pragma unroll
        for (int jx = 0; jx < 4; jx++) acc[i][jx] += a[i] * b[jx];
    }
  }

  float bv[4];
  #pragma unroll
  for (int jx = 0; jx < 4; jx++){
    int bidx = j0 + tj*4 + jx;
    if (OMAP == 3 && bidx > hg*32 - 1) bidx = hg*32 - 1;   // clamped values never stored
    bv[jx] = isf32 ? ((const float*)Bv)[boff + bidx] : bf2f(((const u16*)Bv)[boff + bidx]);
  }

  if (OMAP == 3){
    // -------- retile epilogue: tile(64 hw x 64 col) -> Vt[gs][h][d][w] --------
    __syncthreads();
    #pragma unroll
    for (int i = 0; i < 4; i++)
      #pragma unroll
      for (int jx = 0; jx < 4; jx++)
        stile[(tm*4 + i)*66 + (tj*4 + jx)] = f2bf(scale * (acc[i][jx] + bv[jx]));
    __syncthreads();
    int hw_i = tid & 63;
    int m    = m0 + hw_i;
    int nn   = m / 9216;
    int hwin = m - nn*9216;
    int hh   = hwin / 96, ww = hwin - hh*96;
    #pragma unroll
    for (int e = 0; e < 16; e++){
      int d_col = (tid >> 6) * 16 + e;   // 0..63
      int col   = j0 + d_col;
      if (col < hg*32){
        int gsv = nn*hg + (col >> 5), d = col & 31;
        ((u16*)Yv)[ (((size_t)gsv*96 + hh)*32 + d)*96 + ww ] = stile[hw_i*66 + d_col];
      }
    }
    return;
  }

  #pragma unroll
  for (int i = 0; i < 4; i++){
    int m = m0 + tm*4 + i;
    if (m >= M) continue;
    #pragma unroll
    for (int jx = 0; jx < 4; jx++){
      int col = j0 + tj*4 + jx;
      float vval = scale * (acc[i][jx] + bv[jx]);
      int orow = (OMAP == 1) ? ((m % 300)*8 + (m / 300)) : m;
      size_t oidx = (size_t)orow*256 + col;
      if (OBF == 2){
        if (isf32) ((float*)Yv)[oidx] = vval; else ((u16*)Yv)[oidx] = f2bf(vval);
      } else if (OBF == 1) ((u16*)Yv)[oidx] = f2bf(vval);
      else                 ((float*)Yv)[oidx] = vval;
    }
  }
}

// ---------------------------------------------------------------------------
// K2: attention weights for one head group. Block (128 thr) per (l, gs, row/col)
// ---------------------------------------------------------------------------
__global__ void attn_weights_kernel(const u16* __restrict__ qr, const float* __restrict__ kr,
                                    const u16* __restrict__ qc, const float* __restrict__ kc,
                                    u16* __restrict__ arow, u16* __restrict__ acol,
                                    int head0, int hg){
  __shared__ float ks[96*33];
  __shared__ float qs[32];
  __shared__ float sred[2];
  int l  = blockIdx.x;
  int gs = blockIdx.y;                 // n*hg + hr
  int n  = gs / hg;
  int head = head0 + (gs % hg);
  const u16*   q = blockIdx.z ? qc : qr;
  const float* k = blockIdx.z ? kc : kr;
  u16*         a = blockIdx.z ? acol : arow;
  int tid = threadIdx.x;

  for (int i = tid; i < 96*32; i += 128){
    int w = i >> 5, d = i & 31;
    ks[w*33 + d] = k[((size_t)(n*96) + w)*256 + head*32 + d];
  }
  if (tid < 32) qs[tid] = bf2f(q[((size_t)(n*300) + l)*256 + head*32 + tid]);
  __syncthreads();

  float logit = -1e30f;
  if (tid < 96){
    float s = 0.f;
    #pragma unroll
    for (int d = 0; d < 32; d++) s += qs[d] * ks[tid*33 + d];
    logit = s;
  }
  float m = logit;
  #pragma unroll
  for (int mask = 1; mask < 64; mask <<= 1) m = fmaxf(m, __shfl_xor(m, mask));
  if ((tid & 63) == 0) sred[tid >> 6] = m;
  __syncthreads();
  float Mx = fmaxf(sred[0], sred[1]);
  float e  = (tid < 96) ? __expf(logit - Mx) : 0.f;
  float s  = e;
  #pragma unroll
  for (int mask = 1; mask < 64; mask <<= 1) s += __shfl_xor(s, mask);
  __syncthreads();
  if ((tid & 63) == 0) sred[tid >> 6] = s;
  __syncthreads();
  float S = sred[0] + sred[1];
  if (tid < 96) a[((size_t)gs*300 + l)*96 + tid] = f2bf(e / S);
}

// ---------------------------------------------------------------------------
// K3 (MFMA): attn[n][l][head*32+d] = sum_h acol[l,h] * (sum_w arow[l,w] V[h,w,d])
// Vt bf16 [gs][h(96)][d(32)][w(96)]. Block = (gs, 32-l tile), 256 thr = 4 waves.
// Wave wv: nt = wv&1 (d-halves), hp = wv>>1 (h-parity within 4-h chunk).
// Per h: B-frag(3 ks) read once, feeds both mt (2 MFMAs each) ->
//   T[l,d] for (16l x 16d), scaled by acol[l,h], accumulated in f32.
// A-frags (arow) cached in registers for the whole kernel.
// mfma_f32_16x16x32_bf16: A[m=lane&15][k=quad*8+j]; D col=lane&15,row=quad*4+reg.
// ---------------------------------------------------------------------------
__global__ __launch_bounds__(256) void rcda_core_kernel(
    const u16* __restrict__ arow, const u16* __restrict__ acol,
    const u16* __restrict__ v, float* __restrict__ attn, int head0, int hg){
  __shared__ __align__(16) u16 vt[4*32*104];   // 26624 B, w-stride 104 (bank-safe b128)
  __shared__ __align__(16) u16 aw[32*96];      // 6144 B  (arow tile, bf16)
  __shared__ float cs[32*97];                  // 12416 B (acol tile, f32, pad 97)
  __shared__ float red[2*64*8];                // 4096 B  (cross-wave h reduction)

  int b   = blockIdx.x;
  int xcd = b & 7;
  int jj  = b >> 3;
  int lt  = jj % 10;                 // 0..9  (32-l tiles, 320 padded)
  int gg  = jj / 10;
  int gs  = gg*8 + xcd;              // same-gs blocks share an XCD (L2 locality)
  int n   = gs / hg;
  int head = head0 + (gs % hg);
  int l0  = lt * 32;
  int tid = threadIdx.x;
  int wv  = tid >> 6;
  int ln  = tid & 63;
  int l15 = ln & 15;
  int quad = ln >> 4;
  int nt  = wv & 1;
  int hp  = wv >> 1;

  // ---- stage arow (bf16) + acol (f32) tiles ----
  for (int i = tid; i < 384; i += 256){        // 384 uint4 = 32 rows x 96 u16
    int row = i / 12, rem = i - row*12;
    int lc = l0 + row; if (lc > 299) lc = 299;
    *(uint4*)(aw + row*96 + rem*8) = *(const uint4*)(arow + ((size_t)gs*300 + lc)*96 + rem*8);
  }
  for (int i = tid; i < 3072; i += 256){
    int row = i / 96, col = i - row*96;
    int lc = l0 + row; if (lc > 299) lc = 299;
    cs[row*97 + col] = bf2f(acol[((size_t)gs*300 + lc)*96 + col]);
  }
  __syncthreads();

  // ---- A-fragments in registers: a[mt][ks], l = mt*16 + l15, w = ks*32+quad*8+j
  bf16x8 afr[2][3];
  #pragma unroll
  for (int mt = 0; mt < 2; mt++)
    #pragma unroll
    for (int ks = 0; ks < 3; ks++)
      afr[mt][ks] = *(const bf16x8*)(aw + (mt*16 + l15)*96 + ks*32 + quad*8);

  f32x4 out[2] = {{0.f,0.f,0.f,0.f},{0.f,0.f,0.f,0.f}};   // [mt]
  const u16* vbase = v + (size_t)gs * 96*32*96;

  for (int cc = 0; cc < 24; cc++){
    __syncthreads();
    // stage Vt chunk [4h][32d][96w] (24576B contiguous) -> LDS [4][32][104]
    const uint4* gsrc = (const uint4*)(vbase + (size_t)cc * 4*32*96);
    #pragma unroll
    for (int it = 0; it < 6; it++){
      int i = tid + it*256;                    // 0..1535
      int row = i / 12, rem = i - row*12;      // row: (h*32+d) 0..127
      *(uint4*)((char*)vt + row*208 + rem*16) = gsrc[i];
    }
    __syncthreads();

    #pragma unroll
    for (int hh = 0; hh < 2; hh++){
      int h = hp*2 + hh;                       // 0..3 within chunk
      bf16x8 bfr[3];
      #pragma unroll
      for (int ks = 0; ks < 3; ks++)
        bfr[ks] = *(const bf16x8*)(vt + (h*32 + nt*16 + l15)*104 + ks*32 + quad*8);
      int habs = cc*4 + h;
      #pragma unroll
      for (int mt = 0; mt < 2; mt++){
        f32x4 t = {0.f,0.f,0.f,0.f};
        t = __builtin_amdgcn_mfma_f32_16x16x32_bf16(afr[mt][0], bfr[0], t, 0,0,0);
        t = __builtin_amdgcn_mfma_f32_16x16x32_bf16(afr[mt][1], bfr[1], t, 0,0,0);
        t = __builtin_amdgcn_mfma_f32_16x16x32_bf16(afr[mt][2], bfr[2], t, 0,0,0);
        #pragma unroll
        for (int reg = 0; reg < 4; reg++){
          float sc = cs[(mt*16 + quad*4 + reg)*97 + habs];
          out[mt][reg] += sc * t[reg];
        }
      }
    }
  }

  // ---- cross-wave (h-parity) reduction + store ----
  __syncthreads();
  if (hp == 1){
    float* r = red + ((size_t)(nt*64 + ln))*8;
    #pragma unroll
    for (int mt = 0; mt < 2; mt++)
      #pragma unroll
      for (int reg = 0; reg < 4; reg++) r[mt*4 + reg] = out[mt][reg];
  }
  __syncthreads();
  if (hp == 0){
    const float* r = red + ((size_t)(nt*64 + ln))*8;
    #pragma unroll
    for (int mt = 0; mt < 2; mt++){
      #pragma unroll
      for (int reg = 0; reg < 4; reg++){
        int l = l0 + mt*16 + quad*4 + reg;
        if (l < 300)
          attn[((size_t)(n*300) + l)*256 + head*32 + nt*16 + l15] = out[mt][reg] + r[mt*4 + reg];
      }
    }
  }
}

// ---------------------------------------------------------------------------
// Workspace: flag(256B) | Vt_slab | arow | acol | qr | qc | krm | kcm | kr | kc | attn
// need(hg) = hg*5,640,192 + 8,061,184 bytes
// ---------------------------------------------------------------------------
extern "C" void kernel_launch(void* const* d_in, const int* in_sizes, int n_in,
                              void* d_out, int out_size, void* d_ws, size_t ws_size,
                              hipStream_t stream){
  const void* query_row = d_in[0];
  const void* query_col = d_in[1];
  const void* key_row   = d_in[2];
  const void* key_col   = d_in[3];
  const void* value     = d_in[4];
  const void* in_w      = d_in[5];
  const void* in_b      = d_in[6];
  const void* out_w     = d_in[7];
  const void* out_b     = d_in[8];

  int hg = 1;
  {
    const size_t fixed = 8061184, per = 5640192;
    if      (ws_size >= fixed + 8*per) hg = 8;
    else if (ws_size >= fixed + 4*per) hg = 4;
    else if (ws_size >= fixed + 2*per) hg = 2;
    else                               hg = 1;
  }

  char* ws = (char*)d_ws;
  int*  flag = (int*)ws;
  size_t SV = (size_t)hg * 8 * 9216 * 32 * 2;  // Vt slab bf16
  size_t SA = (size_t)hg * 8 * 300 * 96 * 2;   // a slab bf16
  size_t off = 256;
  u16*   v_slab = (u16*)(ws + off); off += SV;
  u16*   arow   = (u16*)(ws + off); off += SA;
  u16*   acol   = (u16*)(ws + off); off += SA;
  u16*   qr     = (u16*)(ws + off); off += 1228800;
  u16*   qc     = (u16*)(ws + off); off += 1228800;
  float* krm    = (float*)(ws + off); off += 786432;
  float* kcm    = (float*)(ws + off); off += 786432;
  float* kr     = (float*)(ws + off); off += 786432;
  float* kc     = (float*)(ws + off); off += 786432;
  float* attn   = (float*)(ws + off); off += 2457600;

  // D0: dtype detection (flag=1 -> raw inputs are f32)
  detect_kernel<<<1, 64, 0, stream>>>((const u16*)in_b, flag);

  // K0: key means (mean commutes with the affine projection)
  means_kernel<<<dim3(96, 2), 256, 0, stream>>>(key_row, key_col, krm, kcm, flag);

  // K1: q projections (bf16 ws out) and mean-key projections (f32 ws out)
  gemm256_kernel<2,1,0><<<dim3(38, 4), 256, 0, stream>>>(query_row, in_w, 0, in_b, 0,   qr, 2400, kScale, 0, hg, flag);
  gemm256_kernel<2,1,0><<<dim3(38, 4), 256, 0, stream>>>(query_col, in_w, 1, in_b, 256, qc, 2400, kScale, 0, hg, flag);
  gemm256_kernel<0,0,0><<<dim3(12, 4), 256, 0, stream>>>(krm,       in_w, 2, in_b, 512, kr, 768,  1.f,    0, hg, flag);
  gemm256_kernel<0,0,0><<<dim3(12, 4), 256, 0, stream>>>(kcm,       in_w, 3, in_b, 768, kc, 768,  1.f,    0, hg, flag);

  // Per head group: v-proj slice (-> transposed Vt slab) -> softmax -> MFMA core
  for (int head0 = 0; head0 < 8; head0 += hg){
    int gy = (hg*32 + 63) / 64;   // 1,1,2,4 for hg=1,2,4,8
    gemm256_kernel<2,1,3><<<dim3(1152, gy), 256, 0, stream>>>(
        value, in_w, 4, in_b, 1024 + head0*32, v_slab, 73728, 1.f, head0, hg, flag);
    attn_weights_kernel<<<dim3(300, 8*hg, 2), 128, 0, stream>>>(qr, kr, qc, kc, arow, acol, head0, hg);
    rcda_core_kernel<<<dim3(10 * 8 * hg), 256, 0, stream>>>(arow, acol, v_slab, attn, head0, hg);
  }

  // K4: output projection, remap (n,l) -> row l*8+n, out dtype per flag
  gemm256_kernel<0,2,1><<<dim3(38, 4), 256, 0, stream>>>(attn, out_w, 0, out_b, 0, d_out, 2400, 1.f, 0, hg, flag);
}

// Round 5
// 404.764 us; speedup vs baseline: 2.3448x; 1.4902x over previous
//
#include <hip/hip_runtime.h>
#include <stdint.h>

typedef unsigned short u16;
typedef unsigned int   u32;
typedef __attribute__((ext_vector_type(8))) short bf16x8;
typedef __attribute__((ext_vector_type(4))) float f32x4;

static constexpr float kScale = 0.17677669529663687f; // HD^-0.5

// ---------- bf16 helpers (bf16 carried as u16) ----------
__device__ __forceinline__ float bfl(u32 dw){ union{u32 u; float f;} x; x.u = dw << 16;        return x.f; }
__device__ __forceinline__ float bfh(u32 dw){ union{u32 u; float f;} x; x.u = dw & 0xffff0000u; return x.f; }
__device__ __forceinline__ float bf2f(u16 v){ union{u32 u; float f;} x; x.u = ((u32)v) << 16;  return x.f; }
__device__ __forceinline__ u16  f2bf(float f){
  union{float f; u32 u;} x; x.f = f;
  u32 r = x.u + 0x7fffu + ((x.u >> 16) & 1u);  // RNE
  return (u16)(r >> 16);
}

// ---------------------------------------------------------------------------
// D0: dtype detect. flag=1 means "inputs are f32".
// ---------------------------------------------------------------------------
__global__ void detect_kernel(const u16* __restrict__ bias, int* __restrict__ flag){
  int tid = threadIdx.x;               // 64 threads
  u16 raw = bias[tid * 2];
  int big = (fabsf(bf2f(raw)) > 1e6f) ? 1 : 0;
  if ((raw & 0x7F80u) == 0x7F80u) big = 1;   // NaN/Inf bit pattern
  #pragma unroll
  for (int m = 1; m < 64; m <<= 1) big |= __shfl_xor(big, m);
  if (tid == 0) *flag = big;
}

// ---------------------------------------------------------------------------
// K0: row/col means of key_row (over h) and key_col (over w). f32 out.
// ---------------------------------------------------------------------------
__global__ void means_kernel(const void* __restrict__ key_row, const void* __restrict__ key_col,
                             float* __restrict__ krm, float* __restrict__ kcm,
                             const int* __restrict__ flag){
  const bool isf32 = (*flag != 0);
  int g   = blockIdx.x * 256 + threadIdx.x;  // 0..24575
  int c8  = (g & 31) * 8;
  int ri  = g >> 5;                          // 0..767
  int rw  = ri % 96;
  int n   = ri / 96;
  float acc[8];
  #pragma unroll
  for (int i = 0; i < 8; i++) acc[i] = 0.f;

  size_t base, stride;
  const void* src;
  float* dst;
  if (blockIdx.y == 0){         // krm: mean over h; rw = w
    src    = key_row;
    base   = ((size_t)(n*96)*96 + rw)*256 + c8;
    stride = (size_t)96*256;
    dst    = krm + ((size_t)(n*96) + rw)*256 + c8;
  } else {                      // kcm: mean over w; rw = h
    src    = key_col;
    base   = ((size_t)(n*96) + rw)*(size_t)(96*256) + c8;
    stride = 256;
    dst    = kcm + ((size_t)(n*96) + rw)*256 + c8;
  }

  if (isf32){
    const float* p = (const float*)src + base;
    for (int t = 0; t < 96; t++){
      float4 f0 = *(const float4*)(p + t*stride);
      float4 f1 = *(const float4*)(p + t*stride + 4);
      acc[0]+=f0.x; acc[1]+=f0.y; acc[2]+=f0.z; acc[3]+=f0.w;
      acc[4]+=f1.x; acc[5]+=f1.y; acc[6]+=f1.z; acc[7]+=f1.w;
    }
  } else {
    const u16* p = (const u16*)src + base;
    for (int t = 0; t < 96; t++){
      uint4 u = *(const uint4*)(p + t*stride);
      acc[0]+=bfl(u.x); acc[1]+=bfh(u.x); acc[2]+=bfl(u.y); acc[3]+=bfh(u.y);
      acc[4]+=bfl(u.z); acc[5]+=bfh(u.z); acc[6]+=bfl(u.w); acc[7]+=bfh(u.w);
    }
  }
  #pragma unroll
  for (int i = 0; i < 8; i++) dst[i] = acc[i] * (1.f/96.f);
}

// ---------------------------------------------------------------------------
// K1 (MFMA): Y[m][j] = scale*( sum_k X[m][k]*W[j][k] + b[j] ), K=256.
// Tile 64x64, 256 thr = 4 waves; wave (mh=wv&1, nh=wv>>1) owns 32x32 via
// 2x2 mfma_f32_16x16x32_bf16; K in 8 chunks of 32 staged to LDS as bf16.
// XK: 0 = X is ws f32, 2 = X raw input (dtype per flag). W/bias raw per flag.
// OBF: 0 f32 out, 1 bf16 out, 2 dtype-per-flag out.
// OMAP 0: row-major [m][256]
// OMAP 1: out-proj remap m=(n*300+l) -> row l*8+n
// OMAP 3: v-proj slice -> TRANSPOSED slab Vt[gs][h][d][w] via LDS retile
//         (W row = head0*32+col; gs = nn*hg + col>>5, d = col&31)
// ---------------------------------------------------------------------------
template<int XK, int OBF, int OMAP>
__global__ __launch_bounds__(256) void mfma_proj_kernel(
    const void* __restrict__ Xv,
    const void* __restrict__ Wv, int wslice,
    const void* __restrict__ Bv, int boff,
    void* __restrict__ Yv,
    int M, float scale, int head0, int hg,
    const int* __restrict__ flag){
  const bool isf32 = (*flag != 0);
  const bool xf32  = (XK == 0) || isf32;
  __shared__ __align__(16) u16 Xs[64*40];     // 5120 B, stride 40 u16 (80 B)
  __shared__ __align__(16) u16 Ws[64*40];
  __shared__ u16 stile[64*66];                // OMAP3 retile epilogue

  int tid = threadIdx.x;
  int m0  = blockIdx.x * 64;
  int j0  = blockIdx.y * 64;
  int wv  = tid >> 6;
  int ln  = tid & 63;
  int l15 = ln & 15;
  int quad = ln >> 4;
  int mh  = wv & 1;
  int nh  = wv >> 1;

  int srow = tid >> 2;          // 0..63 staging row
  int sko  = (tid & 3) * 8;     // 0,8,16,24

  f32x4 acc[2][2] = {{{0.f,0.f,0.f,0.f},{0.f,0.f,0.f,0.f}},
                     {{0.f,0.f,0.f,0.f},{0.f,0.f,0.f,0.f}}};

  int gm = m0 + srow;
  int wrow = j0 + srow;
  if (OMAP == 3){ wrow += head0*32; if (wrow > 255) wrow = 255; }

  for (int p = 0; p < 8; p++){
    int k0 = p * 32;
    u16 xl[8], wl[8];
    if (gm < M){
      size_t xoff = (size_t)gm*256 + k0 + sko;
      if (xf32){
        const float* xp = (const float*)Xv + xoff;
        float4 f0 = *(const float4*)xp;
        float4 f1 = *(const float4*)(xp + 4);
        xl[0]=f2bf(f0.x); xl[1]=f2bf(f0.y); xl[2]=f2bf(f0.z); xl[3]=f2bf(f0.w);
        xl[4]=f2bf(f1.x); xl[5]=f2bf(f1.y); xl[6]=f2bf(f1.z); xl[7]=f2bf(f1.w);
      } else {
        *(uint4*)xl = *(const uint4*)((const u16*)Xv + xoff);
      }
    } else {
      #pragma unroll
      for (int i = 0; i < 8; i++) xl[i] = 0;
    }
    {
      size_t woff = (size_t)wslice*65536 + (size_t)wrow*256 + k0 + sko;
      if (isf32){
        const float* wp = (const float*)Wv + woff;
        float4 f0 = *(const float4*)wp;
        float4 f1 = *(const float4*)(wp + 4);
        wl[0]=f2bf(f0.x); wl[1]=f2bf(f0.y); wl[2]=f2bf(f0.z); wl[3]=f2bf(f0.w);
        wl[4]=f2bf(f1.x); wl[5]=f2bf(f1.y); wl[6]=f2bf(f1.z); wl[7]=f2bf(f1.w);
      } else {
        *(uint4*)wl = *(const uint4*)((const u16*)Wv + woff);
      }
    }
    __syncthreads();
    *(uint4*)(Xs + srow*40 + sko) = *(uint4*)xl;
    *(uint4*)(Ws + srow*40 + sko) = *(uint4*)wl;
    __syncthreads();

    bf16x8 a0 = *(const bf16x8*)(Xs + (mh*32 +      l15)*40 + quad*8);
    bf16x8 a1 = *(const bf16x8*)(Xs + (mh*32 + 16 + l15)*40 + quad*8);
    bf16x8 b0 = *(const bf16x8*)(Ws + (nh*32 +      l15)*40 + quad*8);
    bf16x8 b1 = *(const bf16x8*)(Ws + (nh*32 + 16 + l15)*40 + quad*8);
    acc[0][0] = __builtin_amdgcn_mfma_f32_16x16x32_bf16(a0, b0, acc[0][0], 0,0,0);
    acc[0][1] = __builtin_amdgcn_mfma_f32_16x16x32_bf16(a0, b1, acc[0][1], 0,0,0);
    acc[1][0] = __builtin_amdgcn_mfma_f32_16x16x32_bf16(a1, b0, acc[1][0], 0,0,0);
    acc[1][1] = __builtin_amdgcn_mfma_f32_16x16x32_bf16(a1, b1, acc[1][1], 0,0,0);
  }

  // bias per tj (col depends only on tj, l15)
  float bv[2];
  #pragma unroll
  for (int tj = 0; tj < 2; tj++){
    int bidx = j0 + nh*32 + tj*16 + l15;
    if (OMAP == 3 && bidx > hg*32 - 1) bidx = hg*32 - 1;  // clamped never stored
    bv[tj] = isf32 ? ((const float*)Bv)[boff + bidx] : bf2f(((const u16*)Bv)[boff + bidx]);
  }

  if (OMAP == 3){
    __syncthreads();
    #pragma unroll
    for (int ti = 0; ti < 2; ti++)
      #pragma unroll
      for (int tj = 0; tj < 2; tj++)
        #pragma unroll
        for (int reg = 0; reg < 4; reg++)
          stile[(mh*32 + ti*16 + quad*4 + reg)*66 + nh*32 + tj*16 + l15] =
              f2bf(scale * (acc[ti][tj][reg] + bv[tj]));
    __syncthreads();
    int hw_i = tid & 63;
    int m    = m0 + hw_i;
    int nn   = m / 9216;
    int hwin = m - nn*9216;
    int hh   = hwin / 96, ww = hwin - hh*96;
    #pragma unroll
    for (int e = 0; e < 16; e++){
      int d_col = (tid >> 6) * 16 + e;   // 0..63
      int col   = j0 + d_col;
      if (col < hg*32){
        int gsv = nn*hg + (col >> 5), d = col & 31;
        ((u16*)Yv)[ (((size_t)gsv*96 + hh)*32 + d)*96 + ww ] = stile[hw_i*66 + d_col];
      }
    }
    return;
  }

  #pragma unroll
  for (int ti = 0; ti < 2; ti++)
    #pragma unroll
    for (int tj = 0; tj < 2; tj++)
      #pragma unroll
      for (int reg = 0; reg < 4; reg++){
        int m = m0 + mh*32 + ti*16 + quad*4 + reg;
        if (m >= M) continue;
        int col = j0 + nh*32 + tj*16 + l15;
        float vval = scale * (acc[ti][tj][reg] + bv[tj]);
        int orow = (OMAP == 1) ? ((m % 300)*8 + (m / 300)) : m;
        size_t oidx = (size_t)orow*256 + col;
        if (OBF == 2){
          if (isf32) ((float*)Yv)[oidx] = vval; else ((u16*)Yv)[oidx] = f2bf(vval);
        } else if (OBF == 1) ((u16*)Yv)[oidx] = f2bf(vval);
        else                 ((float*)Yv)[oidx] = vval;
      }
}

// ---------------------------------------------------------------------------
// K2: attention weights. Single-wave blocks; grid (10 l-tiles x 30, gs, rc).
// lane w holds k[w][0..31] in regs (lanes<32 also hold w+64); 30 q-rows
// staged in LDS once; softmax fully in-wave (no barriers in l-loop).
// ---------------------------------------------------------------------------
__global__ __launch_bounds__(64) void attn_weights_kernel(
    const u16* __restrict__ qr, const float* __restrict__ kr,
    const u16* __restrict__ qc, const float* __restrict__ kc,
    u16* __restrict__ arow, u16* __restrict__ acol,
    int head0, int hg){
  __shared__ float qs[30*32];
  int lt = blockIdx.x;                 // 0..9
  int gs = blockIdx.y;                 // n*hg + hr
  int n  = gs / hg;
  int head = head0 + (gs % hg);
  const u16*   q = blockIdx.z ? qc : qr;
  const float* k = blockIdx.z ? kc : kr;
  u16*         a = blockIdx.z ? acol : arow;
  int lane = threadIdx.x;
  int l0   = lt * 30;

  for (int i = lane; i < 960; i += 64){
    int li = i >> 5, d = i & 31;
    qs[i] = bf2f(q[((size_t)(n*300) + l0 + li)*256 + head*32 + d]);
  }

  bool has2 = (lane < 32);
  float k1[32], k2[32];
  {
    const float* kp = k + ((size_t)(n*96) + lane)*256 + head*32;
    #pragma unroll
    for (int d4 = 0; d4 < 8; d4++){
      float4 f = *(const float4*)(kp + d4*4);
      k1[d4*4+0]=f.x; k1[d4*4+1]=f.y; k1[d4*4+2]=f.z; k1[d4*4+3]=f.w;
    }
    int w2c = has2 ? (64 + lane) : 95;
    const float* kp2 = k + ((size_t)(n*96) + w2c)*256 + head*32;
    #pragma unroll
    for (int d4 = 0; d4 < 8; d4++){
      float4 f = *(const float4*)(kp2 + d4*4);
      k2[d4*4+0]=f.x; k2[d4*4+1]=f.y; k2[d4*4+2]=f.z; k2[d4*4+3]=f.w;
    }
  }
  __syncthreads();

  for (int li = 0; li < 30; li++){
    const float* qv = qs + li*32;
    float s1 = 0.f, s2 = 0.f;
    #pragma unroll
    for (int d4 = 0; d4 < 8; d4++){
      float4 f = *(const float4*)(qv + d4*4);
      s1 += f.x*k1[d4*4+0] + f.y*k1[d4*4+1] + f.z*k1[d4*4+2] + f.w*k1[d4*4+3];
      s2 += f.x*k2[d4*4+0] + f.y*k2[d4*4+1] + f.z*k2[d4*4+2] + f.w*k2[d4*4+3];
    }
    float m = fmaxf(s1, has2 ? s2 : -1e30f);
    #pragma unroll
    for (int mask = 1; mask < 64; mask <<= 1) m = fmaxf(m, __shfl_xor(m, mask));
    float e1 = __expf(s1 - m);
    float e2 = has2 ? __expf(s2 - m) : 0.f;
    float s  = e1 + e2;
    #pragma unroll
    for (int mask = 1; mask < 64; mask <<= 1) s += __shfl_xor(s, mask);
    float inv = 1.f / s;
    u16* dst = a + ((size_t)gs*300 + l0 + li)*96;
    dst[lane] = f2bf(e1 * inv);
    if (has2) dst[64 + lane] = f2bf(e2 * inv);
  }
}

// ---------------------------------------------------------------------------
// K3 (MFMA): attn[n][l][head*32+d] = sum_h acol[l,h] * (sum_w arow[l,w] V[h,w,d])
// Vt bf16 [gs][h(96)][d(32)][w(96)]. Block = (gs, 32-l tile), 256 thr = 4 waves.
// ---------------------------------------------------------------------------
__global__ __launch_bounds__(256) void rcda_core_kernel(
    const u16* __restrict__ arow, const u16* __restrict__ acol,
    const u16* __restrict__ v, float* __restrict__ attn, int head0, int hg){
  __shared__ __align__(16) u16 vt[4*32*104];   // 26624 B, w-stride 104
  __shared__ __align__(16) u16 aw[32*96];      // 6144 B
  __shared__ float cs[32*97];                  // 12416 B
  __shared__ float red[2*64*8];                // 4096 B

  int b   = blockIdx.x;
  int xcd = b & 7;
  int jj  = b >> 3;
  int lt  = jj % 10;
  int gg  = jj / 10;
  int gs  = gg*8 + xcd;
  int n   = gs / hg;
  int head = head0 + (gs % hg);
  int l0  = lt * 32;
  int tid = threadIdx.x;
  int wv  = tid >> 6;
  int ln  = tid & 63;
  int l15 = ln & 15;
  int quad = ln >> 4;
  int nt  = wv & 1;
  int hp  = wv >> 1;

  for (int i = tid; i < 384; i += 256){
    int row = i / 12, rem = i - row*12;
    int lc = l0 + row; if (lc > 299) lc = 299;
    *(uint4*)(aw + row*96 + rem*8) = *(const uint4*)(arow + ((size_t)gs*300 + lc)*96 + rem*8);
  }
  for (int i = tid; i < 3072; i += 256){
    int row = i / 96, col = i - row*96;
    int lc = l0 + row; if (lc > 299) lc = 299;
    cs[row*97 + col] = bf2f(acol[((size_t)gs*300 + lc)*96 + col]);
  }
  __syncthreads();

  bf16x8 afr[2][3];
  #pragma unroll
  for (int mt = 0; mt < 2; mt++)
    #pragma unroll
    for (int ks = 0; ks < 3; ks++)
      afr[mt][ks] = *(const bf16x8*)(aw + (mt*16 + l15)*96 + ks*32 + quad*8);

  f32x4 out[2] = {{0.f,0.f,0.f,0.f},{0.f,0.f,0.f,0.f}};
  const u16* vbase = v + (size_t)gs * 96*32*96;

  for (int cc = 0; cc < 24; cc++){
    __syncthreads();
    const uint4* gsrc = (const uint4*)(vbase + (size_t)cc * 4*32*96);
    #pragma unroll
    for (int it = 0; it < 6; it++){
      int i = tid + it*256;
      int row = i / 12, rem = i - row*12;
      *(uint4*)((char*)vt + row*208 + rem*16) = gsrc[i];
    }
    __syncthreads();

    #pragma unroll
    for (int hh = 0; hh < 2; hh++){
      int h = hp*2 + hh;
      bf16x8 bfr[3];
      #pragma unroll
      for (int ks = 0; ks < 3; ks++)
        bfr[ks] = *(const bf16x8*)(vt + (h*32 + nt*16 + l15)*104 + ks*32 + quad*8);
      int habs = cc*4 + h;
      #pragma unroll
      for (int mt = 0; mt < 2; mt++){
        f32x4 t = {0.f,0.f,0.f,0.f};
        t = __builtin_amdgcn_mfma_f32_16x16x32_bf16(afr[mt][0], bfr[0], t, 0,0,0);
        t = __builtin_amdgcn_mfma_f32_16x16x32_bf16(afr[mt][1], bfr[1], t, 0,0,0);
        t = __builtin_amdgcn_mfma_f32_16x16x32_bf16(afr[mt][2], bfr[2], t, 0,0,0);
        #pragma unroll
        for (int reg = 0; reg < 4; reg++){
          float sc = cs[(mt*16 + quad*4 + reg)*97 + habs];
          out[mt][reg] += sc * t[reg];
        }
      }
    }
  }

  __syncthreads();
  if (hp == 1){
    float* r = red + ((size_t)(nt*64 + ln))*8;
    #pragma unroll
    for (int mt = 0; mt < 2; mt++)
      #pragma unroll
      for (int reg = 0; reg < 4; reg++) r[mt*4 + reg] = out[mt][reg];
  }
  __syncthreads();
  if (hp == 0){
    const float* r = red + ((size_t)(nt*64 + ln))*8;
    #pragma unroll
    for (int mt = 0; mt < 2; mt++){
      #pragma unroll
      for (int reg = 0; reg < 4; reg++){
        int l = l0 + mt*16 + quad*4 + reg;
        if (l < 300)
          attn[((size_t)(n*300) + l)*256 + head*32 + nt*16 + l15] = out[mt][reg] + r[mt*4 + reg];
      }
    }
  }
}

// ---------------------------------------------------------------------------
// Workspace: flag(256B) | Vt_slab | arow | acol | qr | qc | krm | kcm | kr | kc | attn
// need(hg) = hg*5,640,192 + 8,061,184 bytes
// ---------------------------------------------------------------------------
extern "C" void kernel_launch(void* const* d_in, const int* in_sizes, int n_in,
                              void* d_out, int out_size, void* d_ws, size_t ws_size,
                              hipStream_t stream){
  const void* query_row = d_in[0];
  const void* query_col = d_in[1];
  const void* key_row   = d_in[2];
  const void* key_col   = d_in[3];
  const void* value     = d_in[4];
  const void* in_w      = d_in[5];
  const void* in_b      = d_in[6];
  const void* out_w     = d_in[7];
  const void* out_b     = d_in[8];

  int hg = 1;
  {
    const size_t fixed = 8061184, per = 5640192;
    if      (ws_size >= fixed + 8*per) hg = 8;
    else if (ws_size >= fixed + 4*per) hg = 4;
    else if (ws_size >= fixed + 2*per) hg = 2;
    else                               hg = 1;
  }

  char* ws = (char*)d_ws;
  int*  flag = (int*)ws;
  size_t SV = (size_t)hg * 8 * 9216 * 32 * 2;  // Vt slab bf16
  size_t SA = (size_t)hg * 8 * 300 * 96 * 2;   // a slab bf16
  size_t off = 256;
  u16*   v_slab = (u16*)(ws + off); off += SV;
  u16*   arow   = (u16*)(ws + off); off += SA;
  u16*   acol   = (u16*)(ws + off); off += SA;
  u16*   qr     = (u16*)(ws + off); off += 1228800;
  u16*   qc     = (u16*)(ws + off); off += 1228800;
  float* krm    = (float*)(ws + off); off += 786432;
  float* kcm    = (float*)(ws + off); off += 786432;
  float* kr     = (float*)(ws + off); off += 786432;
  float* kc     = (float*)(ws + off); off += 786432;
  float* attn   = (float*)(ws + off); off += 2457600;

  // D0: dtype detection (flag=1 -> raw inputs are f32)
  detect_kernel<<<1, 64, 0, stream>>>((const u16*)in_b, flag);

  // K0: key means (mean commutes with the affine projection)
  means_kernel<<<dim3(96, 2), 256, 0, stream>>>(key_row, key_col, krm, kcm, flag);

  // K1: projections (all MFMA)
  mfma_proj_kernel<2,1,0><<<dim3(38, 4), 256, 0, stream>>>(query_row, in_w, 0, in_b, 0,   qr, 2400, kScale, 0, hg, flag);
  mfma_proj_kernel<2,1,0><<<dim3(38, 4), 256, 0, stream>>>(query_col, in_w, 1, in_b, 256, qc, 2400, kScale, 0, hg, flag);
  mfma_proj_kernel<0,0,0><<<dim3(12, 4), 256, 0, stream>>>(krm,       in_w, 2, in_b, 512, kr, 768,  1.f,    0, hg, flag);
  mfma_proj_kernel<0,0,0><<<dim3(12, 4), 256, 0, stream>>>(kcm,       in_w, 3, in_b, 768, kc, 768,  1.f,    0, hg, flag);

  // Per head group: v-proj (-> transposed Vt slab) -> softmax -> MFMA core
  for (int head0 = 0; head0 < 8; head0 += hg){
    int gy = (hg*32 + 63) / 64;   // 1,1,2,4 for hg=1,2,4,8
    mfma_proj_kernel<2,1,3><<<dim3(1152, gy), 256, 0, stream>>>(
        value, in_w, 4, in_b, 1024 + head0*32, v_slab, 73728, 1.f, head0, hg, flag);
    attn_weights_kernel<<<dim3(10, 8*hg, 2), 64, 0, stream>>>(qr, kr, qc, kc, arow, acol, head0, hg);
    rcda_core_kernel<<<dim3(10 * 8 * hg), 256, 0, stream>>>(arow, acol, v_slab, attn, head0, hg);
  }

  // K4: output projection, remap (n,l) -> row l*8+n, out dtype per flag
  mfma_proj_kernel<0,2,1><<<dim3(38, 4), 256, 0, stream>>>(attn, out_w, 0, out_b, 0, d_out, 2400, 1.f, 0, hg, flag);
}